// Round 11
// baseline (250.174 us; speedup 1.0000x reference)
//
#include <hip/hip_runtime.h>
#include <hip/hip_bf16.h>
#include <stdint.h>

typedef __attribute__((ext_vector_type(8))) short bf16x8;
typedef __attribute__((ext_vector_type(8))) unsigned short u16x8;
typedef __attribute__((ext_vector_type(4))) float f32x4;
typedef __attribute__((ext_vector_type(4))) unsigned short u16x4;

#define T_SEQ 2048
#define HID_D 2880
#define KPAD 2944              // 2880 padded to 46*64
#define NH 64
#define NKV 8
#define HD 64
#define QKV_N 5120
#define ATT_N 4096
#define NOPAD 3072             // wo_bf padded N rows
#define WIN 128
#define RSCALE 0.125f
#define MSCALE 1.3465735903f
#define ROPE_TOT (T_SEQ * (NH + NKV) * 32)   // 4718592

__device__ __forceinline__ unsigned short f2bf(float f) {
  union { float f; unsigned u; } v; v.f = f;
  unsigned r = v.u + 0x7fffu + ((v.u >> 16) & 1u);
  return (unsigned short)(r >> 16);
}
__device__ __forceinline__ float bf2f(unsigned short u) {
  union { unsigned u; float f; } v; v.u = ((unsigned)u) << 16;
  return v.f;
}

__device__ __forceinline__ void gload_lds16(const void* g, void* l) {
  __builtin_amdgcn_global_load_lds((const __attribute__((address_space(1))) char*)g,
                                   (__attribute__((address_space(3))) char*)l, 16, 0, 0);
}

// ---------------- fused RMSNorm (blocks 0..2047) + w_qkv->bf16 pad (blocks 2048..3071) ----------------
__global__ __launch_bounds__(256) void pre_kernel(const float* __restrict__ x,
                                                  const float* __restrict__ w,
                                                  unsigned short* __restrict__ t_bf,
                                                  const float* __restrict__ wq_src,
                                                  unsigned short* __restrict__ wq_dst) {
  __shared__ float red[256];
  if (blockIdx.x < 2048) {
    int row = blockIdx.x;
    const float4* xr4 = (const float4*)(x + (size_t)row * HID_D);
    const float4* w4 = (const float4*)w;
    float ss = 0.f;
    for (int i = threadIdx.x; i < 720; i += 256) {
      float4 v = xr4[i];
      ss += v.x * v.x + v.y * v.y + v.z * v.z + v.w * v.w;
    }
    red[threadIdx.x] = ss;
    __syncthreads();
    for (int s = 128; s > 0; s >>= 1) {
      if (threadIdx.x < s) red[threadIdx.x] += red[threadIdx.x + s];
      __syncthreads();
    }
    float rs = rsqrtf(red[0] / (float)HID_D + 1e-5f);
    u16x4* ob = (u16x4*)(t_bf + (size_t)row * KPAD);
    for (int i = threadIdx.x; i < 736; i += 256) {
      u16x4 o = {0, 0, 0, 0};
      if (i < 720) {
        float4 v = xr4[i];
        float4 g = w4[i];
        o = { f2bf(v.x * rs * g.x), f2bf(v.y * rs * g.y),
              f2bf(v.z * rs * g.z), f2bf(v.w * rs * g.w) };
      }
      ob[i] = o;
    }
  } else {
    const int total = QKV_N * 736;
    for (int i = (blockIdx.x - 2048) * 256 + threadIdx.x; i < total; i += 1024 * 256) {
      int c4 = i % 736, row = i / 736;
      u16x4 o = {0, 0, 0, 0};
      if (c4 < 720) {
        float4 v = ((const float4*)wq_src)[(size_t)row * 720 + c4];
        o = { f2bf(v.x), f2bf(v.y), f2bf(v.z), f2bf(v.w) };
      }
      ((u16x4*)wq_dst)[i] = o;
    }
  }
}

// ============ 8-phase 256x256 GEMM body (QKV): bf16 output + bias ============
__device__ __forceinline__ void gemm_body(const unsigned short* __restrict__ A,
                                          const unsigned short* __restrict__ B,
                                          unsigned short* __restrict__ C,
                                          const float* __restrict__ bias,
                                          int N, int ld, int nt,
                                          int nbx, int nstore, int swz,
                                          unsigned short* sA, unsigned short* sB) {
  const int tid = threadIdx.x;
  const int lane = tid & 63, wid = tid >> 6;
  const int wr = wid >> 2, wc = wid & 3;
  const int lq = lane & 15, ro = lane >> 4;

  const int bx = swz % nbx, by = swz / nbx;
  const int m0 = by * 256, n0 = bx * 256;

  const int R0 = tid >> 3;
  const int g0 = (((tid & 7) ^ (R0 & 7)) << 3);
  const size_t aOff = (size_t)(m0 + R0) * ld + g0;
  size_t bOff[2][2];
#pragma unroll
  for (int h = 0; h < 2; ++h)
#pragma unroll
    for (int r = 0; r < 2; ++r) {
      int rr = n0 + h * 128 + r * 64 + R0;
      bOff[h][r] = (size_t)rr * ld + g0;
    }

  const int ck0 = ((ro ^ (lq & 7)) << 3);
  const int ck1 = (((4 + ro) ^ (lq & 7)) << 3);

#define STG_A(BUF, H, KT)                                                        \
  { unsigned short* _d = sA + ((BUF) * 2 + (H)) * 8192 + wid * 512;              \
    const unsigned short* _s = A + aOff + (size_t)((H) * 128) * ld + (KT) * 64;  \
    gload_lds16(_s, _d); gload_lds16(_s + (size_t)64 * ld, _d + 4096); }
#define STG_B(BUF, H, KT)                                                        \
  { unsigned short* _d = sB + ((BUF) * 2 + (H)) * 8192 + wid * 512;              \
    gload_lds16(B + bOff[H][0] + (KT) * 64, _d);                                 \
    gload_lds16(B + bOff[H][1] + (KT) * 64, _d + 4096); }

  bf16x8 aR[8];
  bf16x8 bR0[4], bR1[4];
  f32x4 acc[8][4] = {};

#define LDA(BUF, S)                                                                        \
  { _Pragma("unroll") for (int ii = 0; ii < 4; ++ii) {                                     \
      const int _r = ((BUF) * 2 + wr) * 8192 + ((S) * 64 + ii * 16 + lq) * 64;             \
      aR[ii * 2 + 0] = *(const bf16x8*)&sA[_r + ck0];                                      \
      aR[ii * 2 + 1] = *(const bf16x8*)&sA[_r + ck1]; } }
#define LDB(BUF, NHF, DST)                                                                 \
  { _Pragma("unroll") for (int jj = 0; jj < 2; ++jj) {                                     \
      const int _r = ((BUF) * 2 + (wc >> 1)) * 8192 +                                      \
                     ((wc & 1) * 64 + ((NHF) * 2 + jj) * 16 + lq) * 64;                    \
      DST[jj * 2 + 0] = *(const bf16x8*)&sB[_r + ck0];                                     \
      DST[jj * 2 + 1] = *(const bf16x8*)&sB[_r + ck1]; } }
#define MFMA16(S, NHF, BREG)                                                               \
  { _Pragma("unroll") for (int ii = 0; ii < 4; ++ii)                                       \
    _Pragma("unroll") for (int jj = 0; jj < 2; ++jj)                                       \
    _Pragma("unroll") for (int kk = 0; kk < 2; ++kk)                                       \
      acc[(S) * 4 + ii][(NHF) * 2 + jj] = __builtin_amdgcn_mfma_f32_16x16x32_bf16(         \
          aR[ii * 2 + kk], BREG[jj * 2 + kk], acc[(S) * 4 + ii][(NHF) * 2 + jj], 0, 0, 0); }
#define PH_MID()                                         \
  __builtin_amdgcn_s_barrier();                          \
  asm volatile("s_waitcnt lgkmcnt(0)" ::: "memory");     \
  __builtin_amdgcn_sched_barrier(0);                     \
  __builtin_amdgcn_s_setprio(1)
#define PH_END()                                         \
  __builtin_amdgcn_s_setprio(0);                         \
  __builtin_amdgcn_s_barrier()

  STG_A(0, 0, 0); STG_A(0, 1, 0); STG_B(0, 0, 0); STG_B(0, 1, 0);
  STG_B(1, 0, 1); STG_B(1, 1, 1);
  asm volatile("s_waitcnt vmcnt(4)" ::: "memory");
  __builtin_amdgcn_s_barrier();

  const int niter = nt >> 1;
  for (int it = 0; it < niter; ++it) {
    const int t = it * 2;
    const bool more = (it + 1 < niter);
    LDA(0, 0); LDB(0, 0, bR0); STG_A(1, 0, t + 1);
    PH_MID(); MFMA16(0, 0, bR0); PH_END();
    LDB(0, 1, bR1); STG_A(1, 1, t + 1);
    PH_MID(); MFMA16(0, 1, bR1); PH_END();
    LDA(0, 1); if (more) STG_B(0, 0, t + 2);
    PH_MID(); MFMA16(1, 1, bR1); PH_END();
    if (more) STG_B(0, 1, t + 2);
    PH_MID(); MFMA16(1, 0, bR0);
    __builtin_amdgcn_s_setprio(0);
    if (more) asm volatile("s_waitcnt vmcnt(4)" ::: "memory");
    else      asm volatile("s_waitcnt vmcnt(0)" ::: "memory");
    __builtin_amdgcn_s_barrier();
    LDA(1, 0); LDB(1, 0, bR0); if (more) STG_A(0, 0, t + 2);
    PH_MID(); MFMA16(0, 0, bR0); PH_END();
    LDB(1, 1, bR1); if (more) STG_A(0, 1, t + 2);
    PH_MID(); MFMA16(0, 1, bR1); PH_END();
    LDA(1, 1); if (more) STG_B(1, 0, t + 3);
    PH_MID(); MFMA16(1, 1, bR1); PH_END();
    if (more) STG_B(1, 1, t + 3);
    PH_MID(); MFMA16(1, 0, bR0);
    __builtin_amdgcn_s_setprio(0);
    if (more) asm volatile("s_waitcnt vmcnt(4)" ::: "memory");
    else      asm volatile("s_waitcnt vmcnt(0)" ::: "memory");
    __builtin_amdgcn_s_barrier();
  }
#undef STG_A
#undef STG_B
#undef LDA
#undef LDB
#undef MFMA16
#undef PH_MID
#undef PH_END

#pragma unroll
  for (int fi = 0; fi < 8; ++fi) {
    const int gr = m0 + wr * 128 + fi * 16 + ro * 4;
#pragma unroll
    for (int j = 0; j < 4; ++j) {
      const int gc = n0 + wc * 64 + j * 16 + lq;
      const float bv = bias[gc];
#pragma unroll
      for (int r = 0; r < 4; ++r)
        C[(size_t)(gr + r) * nstore + gc] = f2bf(acc[fi][j][r] + bv);
    }
  }
}

// ---------------- QKV GEMM (160 blocks, 4Mx5N per XCD) + w_o->bf16 pad conversion (96 blocks) ----------------
__global__ __launch_bounds__(512, 2) void qkv_fused_kernel(const unsigned short* __restrict__ A,
                                                           const unsigned short* __restrict__ B,
                                                           unsigned short* __restrict__ C,
                                                           const float* __restrict__ bias,
                                                           const float* __restrict__ wo_src,
                                                           unsigned short* __restrict__ wo_dst) {
  __shared__ unsigned short sA[2 * 2 * 128 * 64];
  __shared__ unsigned short sB[2 * 2 * 128 * 64];
  const int c = blockIdx.x & 7, q = blockIdx.x >> 3;
  if (q < 20) {
    const int by = (c & 1) * 4 + (q & 3);
    const int bx = (c >> 1) * 5 + (q >> 2);
    gemm_body(A, B, C, bias, QKV_N, KPAD, 46, 20, QKV_N, by * 20 + bx, sA, sB);
  } else {
    const int cid = c * 12 + (q - 20);            // 0..95
    const int total = NOPAD * 1024;               // u16x4 units of padded wo_bf
    for (int i = cid * 512 + threadIdx.x; i < total; i += 96 * 512) {
      u16x4 o = {0, 0, 0, 0};
      if (i < HID_D * 1024) {
        float4 v = ((const float4*)wo_src)[i];
        o = { f2bf(v.x), f2bf(v.y), f2bf(v.z), f2bf(v.w) };
      }
      ((u16x4*)wo_dst)[i] = o;
    }
  }
}

// ============ out projection: 128x256 tile, FULL K=4096, 192 blocks ============
__global__ __launch_bounds__(512, 2) void outproj128_kernel(const unsigned short* __restrict__ att,
                                                            const unsigned short* __restrict__ wo,
                                                            float* __restrict__ out,
                                                            const float* __restrict__ b_o,
                                                            const float* __restrict__ x) {
  __shared__ unsigned short sA[2 * 128 * 64];       // 32 KiB
  __shared__ unsigned short sB[3 * 2 * 128 * 64];   // 96 KiB

  const int tid = threadIdx.x;
  const int lane = tid & 63, wid = tid >> 6;
  const int wr = wid >> 2, wc = wid & 3;
  const int lq = lane & 15, ro = lane >> 4;

  const int c = blockIdx.x & 7, q = blockIdx.x >> 3;      // q: 0..23
  const int by = (c & 1) * 8 + (q & 7);
  const int bx = (c >> 1) * 3 + (q >> 3);
  const int m0 = by * 128, n0 = bx * 256;

  const int R0 = tid >> 3;
  const int g0 = (((tid & 7) ^ (R0 & 7)) << 3);
  const size_t aOff = (size_t)(m0 + R0) * ATT_N + g0;
  size_t bOff[2][2];
#pragma unroll
  for (int h = 0; h < 2; ++h)
#pragma unroll
    for (int r = 0; r < 2; ++r) {
      int rr = n0 + h * 128 + r * 64 + R0;    // wo padded to NOPAD rows, no clamp
      bOff[h][r] = (size_t)rr * ATT_N + g0;
    }

  const int ck0 = ((ro ^ (lq & 7)) << 3);
  const int ck1 = (((4 + ro) ^ (lq & 7)) << 3);

#define OSTG_A(BUF, KT)                                                         \
  { unsigned short* _d = sA + (BUF) * 8192 + wid * 512;                         \
    const unsigned short* _s = att + aOff + (size_t)(KT) * 64;                  \
    gload_lds16(_s, _d); gload_lds16(_s + (size_t)64 * ATT_N, _d + 4096); }
#define OSTG_B(BUF, H, KT)                                                      \
  { unsigned short* _d = sB + ((BUF) * 2 + (H)) * 8192 + wid * 512;             \
    gload_lds16(wo + bOff[H][0] + (KT) * 64, _d);                               \
    gload_lds16(wo + bOff[H][1] + (KT) * 64, _d + 4096); }

  bf16x8 aR[8];
  bf16x8 bR0[4], bR1[4];
  f32x4 acc[4][4] = {};

#define OLDA(BUF)                                                                          \
  { _Pragma("unroll") for (int ii = 0; ii < 4; ++ii) {                                     \
      const int _r = (BUF) * 8192 + (wr * 64 + ii * 16 + lq) * 64;                         \
      aR[ii * 2 + 0] = *(const bf16x8*)&sA[_r + ck0];                                      \
      aR[ii * 2 + 1] = *(const bf16x8*)&sA[_r + ck1]; } }
#define OLDB(BUF, NHF, DST)                                                                \
  { _Pragma("unroll") for (int jj = 0; jj < 2; ++jj) {                                     \
      const int _r = ((BUF) * 2 + (wc >> 1)) * 8192 +                                      \
                     ((wc & 1) * 64 + ((NHF) * 2 + jj) * 16 + lq) * 64;                    \
      DST[jj * 2 + 0] = *(const bf16x8*)&sB[_r + ck0];                                     \
      DST[jj * 2 + 1] = *(const bf16x8*)&sB[_r + ck1]; } }
#define OMFMA(NHF, BREG)                                                                   \
  { _Pragma("unroll") for (int ii = 0; ii < 4; ++ii)                                       \
    _Pragma("unroll") for (int jj = 0; jj < 2; ++jj)                                       \
    _Pragma("unroll") for (int kk = 0; kk < 2; ++kk)                                       \
      acc[ii][(NHF) * 2 + jj] = __builtin_amdgcn_mfma_f32_16x16x32_bf16(                   \
          aR[ii * 2 + kk], BREG[jj * 2 + kk], acc[ii][(NHF) * 2 + jj], 0, 0, 0); }
#define OPH_MID()                                        \
  __builtin_amdgcn_s_barrier();                          \
  asm volatile("s_waitcnt lgkmcnt(0)" ::: "memory");     \
  __builtin_amdgcn_sched_barrier(0);                     \
  __builtin_amdgcn_s_setprio(1)
#define OPH_END()                                        \
  __builtin_amdgcn_s_setprio(0);                         \
  __builtin_amdgcn_s_barrier()

  OSTG_B(0, 0, 0); OSTG_B(0, 1, 0); OSTG_A(0, 0);
  OSTG_B(1, 0, 1); OSTG_B(1, 1, 1); OSTG_A(1, 1);
  asm volatile("s_waitcnt vmcnt(6)" ::: "memory");
  __builtin_amdgcn_s_barrier();

  const int nt = 64;
  for (int it = 0; it < nt / 2; ++it) {
    const int T = it * 2;
    const bool more = (T + 2 < nt);
    const int bb0 = T % 3, bb1 = (T + 1) % 3;
    const int bb2 = (T + 2) % 3, bb3 = (T + 3) % 3;
    OLDA(T & 1); OLDB(bb0, 0, bR0);
    if (more) { OSTG_B(bb2, 0, T + 2); OSTG_B(bb2, 1, T + 2); }
    OPH_MID(); OMFMA(0, bR0); OPH_END();
    OLDB(bb0, 1, bR1);
    if (more) OSTG_A(T & 1, T + 2);
    OPH_MID(); OMFMA(1, bR1);
    __builtin_amdgcn_s_setprio(0);
    if (more) asm volatile("s_waitcnt vmcnt(6)" ::: "memory");
    else      asm volatile("s_waitcnt vmcnt(0)" ::: "memory");
    __builtin_amdgcn_s_barrier();
    OLDA((T + 1) & 1); OLDB(bb1, 0, bR0);
    if (more) { OSTG_B(bb3, 0, T + 3); OSTG_B(bb3, 1, T + 3); }
    OPH_MID(); OMFMA(0, bR0); OPH_END();
    OLDB(bb1, 1, bR1);
    if (more) OSTG_A((T + 1) & 1, T + 3);
    OPH_MID(); OMFMA(1, bR1);
    __builtin_amdgcn_s_setprio(0);
    if (more) asm volatile("s_waitcnt vmcnt(6)" ::: "memory");
    else      asm volatile("s_waitcnt vmcnt(0)" ::: "memory");
    __builtin_amdgcn_s_barrier();
  }
#undef OSTG_A
#undef OSTG_B
#undef OLDA
#undef OLDB
#undef OMFMA
#undef OPH_MID
#undef OPH_END

#pragma unroll
  for (int ii = 0; ii < 4; ++ii) {
    const int gr = m0 + wr * 64 + ii * 16 + ro * 4;
#pragma unroll
    for (int j = 0; j < 4; ++j) {
      const int gc = n0 + wc * 64 + j * 16 + lq;
      if (gc < HID_D) {
        const float bv = b_o[gc];
#pragma unroll
        for (int r = 0; r < 4; ++r) {
          size_t off = (size_t)(gr + r) * HID_D + gc;
          out[off] = acc[ii][j][r] + bv + x[off];
        }
      }
    }
  }
}

// ---------------- YaRN RoPE (q & k) -> bf16, reading bf16 qkv ----------------
__global__ __launch_bounds__(256) void ropev_kernel(const unsigned short* __restrict__ qkvb,
                                                    const int* __restrict__ positions,
                                                    unsigned short* __restrict__ qb,
                                                    unsigned short* __restrict__ kb) {
  int idx = blockIdx.x * 256 + threadIdx.x;
  int d = idx & 31;
  int head = (idx >> 5) % (NH + NKV);
  int t = idx / ((NH + NKV) * 32);
  float pw = (float)d * (1.0f / 32.0f);
  float extrap = expf(-pw * 11.9183905733f);
  float interp = extrap * (1.0f / 32.0f);
  float ramp = fminf(fmaxf(((float)d - 8.0f) * 0.1f, 0.0f), 1.0f);
  float invf = interp * ramp + extrap * (1.0f - ramp);
  float fr = (float)positions[t] * invf;
  float s, c;
  sincosf(fr, &s, &c);
  c *= MSCALE;
  s *= MSCALE;
  if (head < NH) {
    const unsigned short* b = qkvb + (size_t)t * QKV_N + head * HD + d;
    float x1 = bf2f(b[0]), x2 = bf2f(b[32]);
    unsigned short* ob = qb + (size_t)t * ATT_N + head * HD + d;
    ob[0] = f2bf(x1 * c - x2 * s);
    ob[32] = f2bf(x2 * c + x1 * s);
  } else {
    int gk = head - NH;
    const unsigned short* b = qkvb + (size_t)t * QKV_N + NH * HD + gk * HD + d;
    float x1 = bf2f(b[0]), x2 = bf2f(b[32]);
    unsigned short* ob = kb + (size_t)t * (NKV * HD) + gk * HD + d;
    ob[0] = f2bf(x1 * c - x2 * s);
    ob[32] = f2bf(x2 * c + x1 * s);
  }
}

// ---------------- V transpose via LDS (coalesced both sides): vt[g][d][t] ----------------
__global__ __launch_bounds__(256) void vtrans_kernel(const unsigned short* __restrict__ qkvb,
                                                     unsigned short* __restrict__ vt) {
  __shared__ unsigned short tile[64][72];   // pitch 144B (multiple of 16)
  const int g = blockIdx.x >> 5;
  const int t0 = (blockIdx.x & 31) << 6;
  const int r = threadIdx.x >> 3;           // 0..31
  const int c8 = (threadIdx.x & 7) << 3;    // 0,8,..,56
  const size_t vbase = (size_t)(NH + NKV) * HD + (size_t)g * HD;
#pragma unroll
  for (int hh = 0; hh < 2; ++hh) {
    int row = r + hh * 32;
    *(u16x8*)&tile[row][c8] =
        *(const u16x8*)(qkvb + (size_t)(t0 + row) * QKV_N + vbase + c8);
  }
  __syncthreads();
  const int d = threadIdx.x >> 2;           // 0..63
  const int ts = (threadIdx.x & 3) << 4;    // 0,16,32,48
  u16x8 v0, v1;
#pragma unroll
  for (int i = 0; i < 8; ++i) { v0[i] = tile[ts + i][d]; v1[i] = tile[ts + 8 + i][d]; }
  unsigned short* dst = vt + (size_t)(g * HD + d) * T_SEQ + t0 + ts;
  *(u16x8*)dst = v0;
  *(u16x8*)(dst + 8) = v1;
}

// ---------------- sliding-window attention with sinks (round-9 body + repacked O store) ----------------
__global__ __launch_bounds__(256) void attn_kernel(const unsigned short* __restrict__ qb,
                                                   const unsigned short* __restrict__ kb,
                                                   const unsigned short* __restrict__ vt,
                                                   const float* __restrict__ sinks,
                                                   unsigned short* __restrict__ att) {
  __shared__ unsigned short orep[4][16][72];   // per-wave O repack tile
  const int lane = threadIdx.x & 63;
  const int wid = threadIdx.x >> 6;
  const int q0 = blockIdx.x * 16;
  const int h = blockIdx.y * 4 + wid;
  const int g = h >> 3;
  const int lq = lane & 15;
  const int ro = lane >> 4;

  bf16x8 bq0, bq1;
  {
    const unsigned short* qp = qb + (size_t)(q0 + lq) * ATT_N + h * HD + ro * 8;
    bq0 = *(const bf16x8*)qp;
    bq1 = *(const bf16x8*)(qp + 32);
  }
  float m_run = sinks[h];
  float l_run = 1.0f;
  f32x4 o0 = {0.f, 0.f, 0.f, 0.f}, o1 = o0, o2 = o0, o3 = o0;
  const int qg = q0 + lq;
  const int jstart = (q0 >= WIN) ? q0 - WIN : 0;

  for (int jt = jstart; jt <= q0; jt += 32) {
    f32x4 st0 = {0.f, 0.f, 0.f, 0.f}, st1 = st0;
    {
      int kr = jt + ((lq >> 2) << 3) + (lq & 3);
      int kr0 = min(kr, T_SEQ - 1);
      int kr1 = min(kr + 4, T_SEQ - 1);
      const unsigned short* kp0 = kb + (size_t)kr0 * (NKV * HD) + g * HD + ro * 8;
      const unsigned short* kp1 = kb + (size_t)kr1 * (NKV * HD) + g * HD + ro * 8;
      bf16x8 ka0a = *(const bf16x8*)kp0;
      bf16x8 ka0b = *(const bf16x8*)(kp0 + 32);
      bf16x8 ka1a = *(const bf16x8*)kp1;
      bf16x8 ka1b = *(const bf16x8*)(kp1 + 32);
      st0 = __builtin_amdgcn_mfma_f32_16x16x32_bf16(ka0a, bq0, st0, 0, 0, 0);
      st0 = __builtin_amdgcn_mfma_f32_16x16x32_bf16(ka0b, bq1, st0, 0, 0, 0);
      st1 = __builtin_amdgcn_mfma_f32_16x16x32_bf16(ka1a, bq0, st1, 0, 0, 0);
      st1 = __builtin_amdgcn_mfma_f32_16x16x32_bf16(ka1b, bq1, st1, 0, 0, 0);
    }
    float p[8];
    float tmax = -3.0e30f;
#pragma unroll
    for (int r = 0; r < 4; ++r) {
      int jg0 = jt + ro * 8 + r;
      int jg1 = jg0 + 4;
      float s0 = (jg0 <= qg && (qg - jg0) < WIN) ? st0[r] * RSCALE : -3.0e30f;
      float s1 = (jg1 <= qg && (qg - jg1) < WIN) ? st1[r] * RSCALE : -3.0e30f;
      p[r] = s0;
      p[r + 4] = s1;
      tmax = fmaxf(tmax, fmaxf(s0, s1));
    }
    tmax = fmaxf(tmax, __shfl_xor(tmax, 16));
    tmax = fmaxf(tmax, __shfl_xor(tmax, 32));
    float m_new = fmaxf(m_run, tmax);
    float rescale = expf(m_run - m_new);
    float psum = 0.f;
    bf16x8 pa;
#pragma unroll
    for (int jj = 0; jj < 8; ++jj) {
      float pe = expf(p[jj] - m_new);
      psum += pe;
      pa[jj] = (short)f2bf(pe);
    }
    psum += __shfl_xor(psum, 16);
    psum += __shfl_xor(psum, 32);
    l_run = l_run * rescale + psum;
    m_run = m_new;
    f32x4 rs4;
#pragma unroll
    for (int r = 0; r < 4; ++r) rs4[r] = __shfl(rescale, ro * 4 + r);
    o0 *= rs4; o1 *= rs4; o2 *= rs4; o3 *= rs4;
    int tb = jt + ro * 8;
    if (tb > T_SEQ - 8) tb = T_SEQ - 8;
    const unsigned short* vp = vt + (size_t)(g * HD + lq) * T_SEQ + tb;
    bf16x8 v0 = *(const bf16x8*)vp;
    bf16x8 v1 = *(const bf16x8*)(vp + 16 * T_SEQ);
    bf16x8 v2 = *(const bf16x8*)(vp + 32 * T_SEQ);
    bf16x8 v3 = *(const bf16x8*)(vp + 48 * T_SEQ);
    o0 = __builtin_amdgcn_mfma_f32_16x16x32_bf16(pa, v0, o0, 0, 0, 0);
    o1 = __builtin_amdgcn_mfma_f32_16x16x32_bf16(pa, v1, o1, 0, 0, 0);
    o2 = __builtin_amdgcn_mfma_f32_16x16x32_bf16(pa, v2, o2, 0, 0, 0);
    o3 = __builtin_amdgcn_mfma_f32_16x16x32_bf16(pa, v3, o3, 0, 0, 0);
  }

  // per-wave LDS repack -> vectorized att stores (same-wave LDS ordering, no barrier)
#pragma unroll
  for (int r = 0; r < 4; ++r) {
    float lr = __shfl(l_run, ro * 4 + r);
    float inv = 1.0f / lr;
    int row = ro * 4 + r;
    orep[wid][row][lq]      = f2bf(o0[r] * inv);
    orep[wid][row][lq + 16] = f2bf(o1[r] * inv);
    orep[wid][row][lq + 32] = f2bf(o2[r] * inv);
    orep[wid][row][lq + 48] = f2bf(o3[r] * inv);
  }
  {
    const int row = lane >> 2;          // 0..15
    const int seg = (lane & 3) << 4;    // 0,16,32,48
    u16x8 w0 = *(const u16x8*)&orep[wid][row][seg];
    u16x8 w1 = *(const u16x8*)&orep[wid][row][seg + 8];
    unsigned short* op = att + (size_t)(q0 + row) * ATT_N + h * HD + seg;
    *(u16x8*)op = w0;
    *(u16x8*)(op + 8) = w1;
  }
}

extern "C" void kernel_launch(void* const* d_in, const int* in_sizes, int n_in,
                              void* d_out, int out_size, void* d_ws, size_t ws_size,
                              hipStream_t stream) {
  const float* x = (const float*)d_in[0];
  const int* pos = (const int*)d_in[1];
  const float* norm_w = (const float*)d_in[2];
  const float* w_qkv = (const float*)d_in[3];
  const float* b_qkv = (const float*)d_in[4];
  const float* w_o = (const float*)d_in[5];
  const float* b_o = (const float*)d_in[6];
  const float* sinks = (const float*)d_in[7];
  float* out = (float*)d_out;

  unsigned short* t_bf = (unsigned short*)d_ws;                        // [2048][2944]
  unsigned short* wq_bf = t_bf + (size_t)T_SEQ * KPAD;                 // [5120][2944]
  unsigned short* wo_bf = wq_bf + (size_t)QKV_N * KPAD;                // [3072][4096]
  unsigned short* qkv_bf = wo_bf + (size_t)NOPAD * ATT_N;              // [2048][5120] bf16
  unsigned short* qb = qkv_bf + (size_t)T_SEQ * QKV_N;                 // [2048][4096]
  unsigned short* kb = qb + (size_t)T_SEQ * ATT_N;                     // [2048][512]
  unsigned short* vt = kb + (size_t)T_SEQ * NKV * HD;                  // [8][64][2048]
  unsigned short* att = vt + (size_t)NKV * HD * T_SEQ;                 // [2048][4096]

  // 1. RMSNorm + w_qkv conversion
  pre_kernel<<<3072, 256, 0, stream>>>(x, norm_w, t_bf, w_qkv, wq_bf);
  // 2. QKV GEMM (160 blocks) + w_o conversion/pad (96 blocks)
  qkv_fused_kernel<<<256, 512, 0, stream>>>(t_bf, wq_bf, qkv_bf, b_qkv, w_o, wo_bf);
  // 3. RoPE (q,k)
  ropev_kernel<<<ROPE_TOT / 256, 256, 0, stream>>>(qkv_bf, pos, qb, kb);
  // 4. V transpose (LDS, coalesced)
  vtrans_kernel<<<256, 256, 0, stream>>>(qkv_bf, vt);
  // 5. attention
  attn_kernel<<<dim3(T_SEQ / 16, NH / 4), 256, 0, stream>>>(qb, kb, vt, sinks, att);
  // 6. out projection: full-K 128x256 tiles, direct store with bias + residual
  outproj128_kernel<<<192, 512, 0, stream>>>(att, wo_bf, out, b_o, x);
}

// Round 12
// 229.176 us; speedup vs baseline: 1.0916x; 1.0916x over previous
//
#include <hip/hip_runtime.h>
#include <hip/hip_bf16.h>
#include <stdint.h>

typedef __attribute__((ext_vector_type(8))) short bf16x8;
typedef __attribute__((ext_vector_type(8))) unsigned short u16x8;
typedef __attribute__((ext_vector_type(4))) float f32x4;
typedef __attribute__((ext_vector_type(4))) unsigned short u16x4;

#define T_SEQ 2048
#define HID_D 2880
#define KPAD 2944              // 2880 padded to 46*64
#define NH 64
#define NKV 8
#define HD 64
#define QKV_N 5120
#define ATT_N 4096
#define NOPAD 3072             // wo_bf region rows (layout constant; only HID_D written)
#define WIN 128
#define RSCALE 0.125f
#define MSCALE 1.3465735903f
#define ROPE_TOT (T_SEQ * (NH + NKV) * 32)   // 4718592

__device__ __forceinline__ unsigned short f2bf(float f) {
  union { float f; unsigned u; } v; v.f = f;
  unsigned r = v.u + 0x7fffu + ((v.u >> 16) & 1u);
  return (unsigned short)(r >> 16);
}
__device__ __forceinline__ float bf2f(unsigned short u) {
  union { unsigned u; float f; } v; v.u = ((unsigned)u) << 16;
  return v.f;
}

__device__ __forceinline__ void gload_lds16(const void* g, void* l) {
  __builtin_amdgcn_global_load_lds((const __attribute__((address_space(1))) char*)g,
                                   (__attribute__((address_space(3))) char*)l, 16, 0, 0);
}

// ---------------- fused RMSNorm (blocks 0..2047) + w_qkv->bf16 pad (blocks 2048..3071) ----------------
__global__ __launch_bounds__(256) void pre_kernel(const float* __restrict__ x,
                                                  const float* __restrict__ w,
                                                  unsigned short* __restrict__ t_bf,
                                                  const float* __restrict__ wq_src,
                                                  unsigned short* __restrict__ wq_dst) {
  __shared__ float red[256];
  if (blockIdx.x < 2048) {
    int row = blockIdx.x;
    const float4* xr4 = (const float4*)(x + (size_t)row * HID_D);
    const float4* w4 = (const float4*)w;
    float ss = 0.f;
    for (int i = threadIdx.x; i < 720; i += 256) {
      float4 v = xr4[i];
      ss += v.x * v.x + v.y * v.y + v.z * v.z + v.w * v.w;
    }
    red[threadIdx.x] = ss;
    __syncthreads();
    for (int s = 128; s > 0; s >>= 1) {
      if (threadIdx.x < s) red[threadIdx.x] += red[threadIdx.x + s];
      __syncthreads();
    }
    float rs = rsqrtf(red[0] / (float)HID_D + 1e-5f);
    u16x4* ob = (u16x4*)(t_bf + (size_t)row * KPAD);
    for (int i = threadIdx.x; i < 736; i += 256) {
      u16x4 o = {0, 0, 0, 0};
      if (i < 720) {
        float4 v = xr4[i];
        float4 g = w4[i];
        o = { f2bf(v.x * rs * g.x), f2bf(v.y * rs * g.y),
              f2bf(v.z * rs * g.z), f2bf(v.w * rs * g.w) };
      }
      ob[i] = o;
    }
  } else {
    const int total = QKV_N * 736;
    for (int i = (blockIdx.x - 2048) * 256 + threadIdx.x; i < total; i += 1024 * 256) {
      int c4 = i % 736, row = i / 736;
      u16x4 o = {0, 0, 0, 0};
      if (c4 < 720) {
        float4 v = ((const float4*)wq_src)[(size_t)row * 720 + c4];
        o = { f2bf(v.x), f2bf(v.y), f2bf(v.z), f2bf(v.w) };
      }
      ((u16x4*)wq_dst)[i] = o;
    }
  }
}

// ============ 8-phase 256x256 GEMM body (QKV): bf16 output + bias ============
__device__ __forceinline__ void gemm_body(const unsigned short* __restrict__ A,
                                          const unsigned short* __restrict__ B,
                                          unsigned short* __restrict__ C,
                                          const float* __restrict__ bias,
                                          int N, int ld, int nt,
                                          int nbx, int nstore, int swz,
                                          unsigned short* sA, unsigned short* sB) {
  const int tid = threadIdx.x;
  const int lane = tid & 63, wid = tid >> 6;
  const int wr = wid >> 2, wc = wid & 3;
  const int lq = lane & 15, ro = lane >> 4;

  const int bx = swz % nbx, by = swz / nbx;
  const int m0 = by * 256, n0 = bx * 256;

  const int R0 = tid >> 3;
  const int g0 = (((tid & 7) ^ (R0 & 7)) << 3);
  const size_t aOff = (size_t)(m0 + R0) * ld + g0;
  size_t bOff[2][2];
#pragma unroll
  for (int h = 0; h < 2; ++h)
#pragma unroll
    for (int r = 0; r < 2; ++r) {
      int rr = n0 + h * 128 + r * 64 + R0;
      bOff[h][r] = (size_t)rr * ld + g0;
    }

  const int ck0 = ((ro ^ (lq & 7)) << 3);
  const int ck1 = (((4 + ro) ^ (lq & 7)) << 3);

#define STG_A(BUF, H, KT)                                                        \
  { unsigned short* _d = sA + ((BUF) * 2 + (H)) * 8192 + wid * 512;              \
    const unsigned short* _s = A + aOff + (size_t)((H) * 128) * ld + (KT) * 64;  \
    gload_lds16(_s, _d); gload_lds16(_s + (size_t)64 * ld, _d + 4096); }
#define STG_B(BUF, H, KT)                                                        \
  { unsigned short* _d = sB + ((BUF) * 2 + (H)) * 8192 + wid * 512;              \
    gload_lds16(B + bOff[H][0] + (KT) * 64, _d);                                 \
    gload_lds16(B + bOff[H][1] + (KT) * 64, _d + 4096); }

  bf16x8 aR[8];
  bf16x8 bR0[4], bR1[4];
  f32x4 acc[8][4] = {};

#define LDA(BUF, S)                                                                        \
  { _Pragma("unroll") for (int ii = 0; ii < 4; ++ii) {                                     \
      const int _r = ((BUF) * 2 + wr) * 8192 + ((S) * 64 + ii * 16 + lq) * 64;             \
      aR[ii * 2 + 0] = *(const bf16x8*)&sA[_r + ck0];                                      \
      aR[ii * 2 + 1] = *(const bf16x8*)&sA[_r + ck1]; } }
#define LDB(BUF, NHF, DST)                                                                 \
  { _Pragma("unroll") for (int jj = 0; jj < 2; ++jj) {                                     \
      const int _r = ((BUF) * 2 + (wc >> 1)) * 8192 +                                      \
                     ((wc & 1) * 64 + ((NHF) * 2 + jj) * 16 + lq) * 64;                    \
      DST[jj * 2 + 0] = *(const bf16x8*)&sB[_r + ck0];                                     \
      DST[jj * 2 + 1] = *(const bf16x8*)&sB[_r + ck1]; } }
#define MFMA16(S, NHF, BREG)                                                               \
  { _Pragma("unroll") for (int ii = 0; ii < 4; ++ii)                                       \
    _Pragma("unroll") for (int jj = 0; jj < 2; ++jj)                                       \
    _Pragma("unroll") for (int kk = 0; kk < 2; ++kk)                                       \
      acc[(S) * 4 + ii][(NHF) * 2 + jj] = __builtin_amdgcn_mfma_f32_16x16x32_bf16(         \
          aR[ii * 2 + kk], BREG[jj * 2 + kk], acc[(S) * 4 + ii][(NHF) * 2 + jj], 0, 0, 0); }
#define PH_MID()                                         \
  __builtin_amdgcn_s_barrier();                          \
  asm volatile("s_waitcnt lgkmcnt(0)" ::: "memory");     \
  __builtin_amdgcn_sched_barrier(0);                     \
  __builtin_amdgcn_s_setprio(1)
#define PH_END()                                         \
  __builtin_amdgcn_s_setprio(0);                         \
  __builtin_amdgcn_s_barrier()

  STG_A(0, 0, 0); STG_A(0, 1, 0); STG_B(0, 0, 0); STG_B(0, 1, 0);
  STG_B(1, 0, 1); STG_B(1, 1, 1);
  asm volatile("s_waitcnt vmcnt(4)" ::: "memory");
  __builtin_amdgcn_s_barrier();

  const int niter = nt >> 1;
  for (int it = 0; it < niter; ++it) {
    const int t = it * 2;
    const bool more = (it + 1 < niter);
    LDA(0, 0); LDB(0, 0, bR0); STG_A(1, 0, t + 1);
    PH_MID(); MFMA16(0, 0, bR0); PH_END();
    LDB(0, 1, bR1); STG_A(1, 1, t + 1);
    PH_MID(); MFMA16(0, 1, bR1); PH_END();
    LDA(0, 1); if (more) STG_B(0, 0, t + 2);
    PH_MID(); MFMA16(1, 1, bR1); PH_END();
    if (more) STG_B(0, 1, t + 2);
    PH_MID(); MFMA16(1, 0, bR0);
    __builtin_amdgcn_s_setprio(0);
    if (more) asm volatile("s_waitcnt vmcnt(4)" ::: "memory");
    else      asm volatile("s_waitcnt vmcnt(0)" ::: "memory");
    __builtin_amdgcn_s_barrier();
    LDA(1, 0); LDB(1, 0, bR0); if (more) STG_A(0, 0, t + 2);
    PH_MID(); MFMA16(0, 0, bR0); PH_END();
    LDB(1, 1, bR1); if (more) STG_A(0, 1, t + 2);
    PH_MID(); MFMA16(0, 1, bR1); PH_END();
    LDA(1, 1); if (more) STG_B(1, 0, t + 3);
    PH_MID(); MFMA16(1, 1, bR1); PH_END();
    if (more) STG_B(1, 1, t + 3);
    PH_MID(); MFMA16(1, 0, bR0);
    __builtin_amdgcn_s_setprio(0);
    if (more) asm volatile("s_waitcnt vmcnt(4)" ::: "memory");
    else      asm volatile("s_waitcnt vmcnt(0)" ::: "memory");
    __builtin_amdgcn_s_barrier();
  }
#undef STG_A
#undef STG_B
#undef LDA
#undef LDB
#undef MFMA16

#pragma unroll
  for (int fi = 0; fi < 8; ++fi) {
    const int gr = m0 + wr * 128 + fi * 16 + ro * 4;
#pragma unroll
    for (int j = 0; j < 4; ++j) {
      const int gc = n0 + wc * 64 + j * 16 + lq;
      const float bv = bias[gc];
#pragma unroll
      for (int r = 0; r < 4; ++r)
        C[(size_t)(gr + r) * nstore + gc] = f2bf(acc[fi][j][r] + bv);
    }
  }
}

// ---------------- QKV GEMM (160 blocks, 4Mx5N per XCD) + w_o->bf16 conversion (96 blocks) ----------------
__global__ __launch_bounds__(512, 2) void qkv_fused_kernel(const unsigned short* __restrict__ A,
                                                           const unsigned short* __restrict__ B,
                                                           unsigned short* __restrict__ C,
                                                           const float* __restrict__ bias,
                                                           const float* __restrict__ wo_src,
                                                           unsigned short* __restrict__ wo_dst) {
  __shared__ unsigned short sA[2 * 2 * 128 * 64];
  __shared__ unsigned short sB[2 * 2 * 128 * 64];
  const int c = blockIdx.x & 7, q = blockIdx.x >> 3;
  if (q < 20) {
    const int by = (c & 1) * 4 + (q & 3);
    const int bx = (c >> 1) * 5 + (q >> 2);
    gemm_body(A, B, C, bias, QKV_N, KPAD, 46, 20, QKV_N, by * 20 + bx, sA, sB);
  } else {
    const int cid = c * 12 + (q - 20);            // 0..95
    const int total = HID_D * 1024;               // float4 count of w_o
    for (int i = cid * 512 + threadIdx.x; i < total; i += 96 * 512) {
      float4 v = ((const float4*)wo_src)[i];
      u16x4 o = { f2bf(v.x), f2bf(v.y), f2bf(v.z), f2bf(v.w) };
      ((u16x4*)wo_dst)[i] = o;
    }
  }
}

// ============ out projection: 128x192 tile, FULL K=4096, 240 blocks (16Mx15N) ============
// A 2-buf (32KB) + B 3-buf (72KB) = 104 KB. 5 gloads/K-tile, counted vmcnt(5).
// 2 phases/K-tile (16 + 8 MFMA). 2880 = 15*192 exactly: no edge handling anywhere.
__global__ __launch_bounds__(512, 2) void outproj192_kernel(const unsigned short* __restrict__ att,
                                                            const unsigned short* __restrict__ wo,
                                                            float* __restrict__ out,
                                                            const float* __restrict__ b_o,
                                                            const float* __restrict__ x) {
  __shared__ unsigned short sA[2 * 128 * 64];       // 32 KiB
  __shared__ unsigned short sB[3 * 192 * 64];       // 72 KiB

  const int tid = threadIdx.x;
  const int lane = tid & 63, wid = tid >> 6;
  const int wr = wid >> 2, wc = wid & 3;            // 2M x 4N waves: 64x48 each
  const int lq = lane & 15, ro = lane >> 4;

  // XCD c owns M-rows {2c, 2c+1} x all 15 N-tiles
  const int c = blockIdx.x & 7, q = blockIdx.x >> 3;      // q: 0..29
  const int by = c * 2 + (q >= 15 ? 1 : 0);
  const int bx = (q >= 15) ? q - 15 : q;
  const int m0 = by * 128, n0 = bx * 192;

  const int R0 = tid >> 3;
  const int g0 = (((tid & 7) ^ (R0 & 7)) << 3);
  const size_t aOff = (size_t)(m0 + R0) * ATT_N + g0;
  size_t bOff[3];
#pragma unroll
  for (int r = 0; r < 3; ++r)
    bOff[r] = (size_t)(n0 + r * 64 + R0) * ATT_N + g0;

  const int ck0 = ((ro ^ (lq & 7)) << 3);
  const int ck1 = (((4 + ro) ^ (lq & 7)) << 3);

#define PSTG_A(BUF, KT)                                                         \
  { unsigned short* _d = sA + (BUF) * 8192 + wid * 512;                         \
    const unsigned short* _s = att + aOff + (size_t)(KT) * 64;                  \
    gload_lds16(_s, _d); gload_lds16(_s + (size_t)64 * ATT_N, _d + 4096); }
#define PSTG_B(BUF, KT)                                                         \
  { unsigned short* _d = sB + (BUF) * 12288 + wid * 512;                        \
    gload_lds16(wo + bOff[0] + (KT) * 64, _d);                                  \
    gload_lds16(wo + bOff[1] + (KT) * 64, _d + 4096);                           \
    gload_lds16(wo + bOff[2] + (KT) * 64, _d + 8192); }

  bf16x8 aR[8];
  bf16x8 b00, b01, b10, b11, b20, b21;
  f32x4 acc[4][3] = {};

#define PLDA(BUF)                                                                          \
  { _Pragma("unroll") for (int ii = 0; ii < 4; ++ii) {                                     \
      const int _r = (BUF) * 8192 + (wr * 64 + ii * 16 + lq) * 64;                         \
      aR[ii * 2 + 0] = *(const bf16x8*)&sA[_r + ck0];                                      \
      aR[ii * 2 + 1] = *(const bf16x8*)&sA[_r + ck1]; } }
#define PLDB(BUF, J, D0, D1)                                                               \
  { const int _r = (BUF) * 12288 + (wc * 48 + (J) * 16 + lq) * 64;                         \
    D0 = *(const bf16x8*)&sB[_r + ck0];                                                    \
    D1 = *(const bf16x8*)&sB[_r + ck1]; }

  // prologue: tiles 0 and 1
  PSTG_B(0, 0); PSTG_A(0, 0);
  PSTG_B(1, 1); PSTG_A(1, 1);
  asm volatile("s_waitcnt vmcnt(5)" ::: "memory");
  __builtin_amdgcn_s_barrier();

  const int nt = 64;                                // K = 4096 / 64
  for (int T = 0; T < nt; ++T) {
    const bool more = (T + 2 < nt);
    const int bb = T % 3, bA = T & 1;
    // P1: A frags + B cols 0,1; stage B(T+2)
    PLDA(bA);
    PLDB(bb, 0, b00, b01);
    PLDB(bb, 1, b10, b11);
    if (more) PSTG_B((T + 2) % 3, T + 2);
    PH_MID();
#pragma unroll
    for (int ii = 0; ii < 4; ++ii) {
      acc[ii][0] = __builtin_amdgcn_mfma_f32_16x16x32_bf16(aR[ii * 2 + 0], b00, acc[ii][0], 0, 0, 0);
      acc[ii][0] = __builtin_amdgcn_mfma_f32_16x16x32_bf16(aR[ii * 2 + 1], b01, acc[ii][0], 0, 0, 0);
      acc[ii][1] = __builtin_amdgcn_mfma_f32_16x16x32_bf16(aR[ii * 2 + 0], b10, acc[ii][1], 0, 0, 0);
      acc[ii][1] = __builtin_amdgcn_mfma_f32_16x16x32_bf16(aR[ii * 2 + 1], b11, acc[ii][1], 0, 0, 0);
    }
    PH_END();
    // P2: B col 2; stage A(T+2); end-of-tile counted wait
    PLDB(bb, 2, b20, b21);
    if (more) PSTG_A((T + 2) & 1, T + 2);
    PH_MID();
#pragma unroll
    for (int ii = 0; ii < 4; ++ii) {
      acc[ii][2] = __builtin_amdgcn_mfma_f32_16x16x32_bf16(aR[ii * 2 + 0], b20, acc[ii][2], 0, 0, 0);
      acc[ii][2] = __builtin_amdgcn_mfma_f32_16x16x32_bf16(aR[ii * 2 + 1], b21, acc[ii][2], 0, 0, 0);
    }
    __builtin_amdgcn_s_setprio(0);
    if (more) asm volatile("s_waitcnt vmcnt(5)" ::: "memory");
    else      asm volatile("s_waitcnt vmcnt(0)" ::: "memory");
    __builtin_amdgcn_s_barrier();
  }
#undef PSTG_A
#undef PSTG_B
#undef PLDA
#undef PLDB
#undef PH_MID
#undef PH_END

  // epilogue: out = acc + b_o + x  (all cols valid: 2880 = 15*192)
#pragma unroll
  for (int ii = 0; ii < 4; ++ii) {
    const int gr = m0 + wr * 64 + ii * 16 + ro * 4;
#pragma unroll
    for (int j = 0; j < 3; ++j) {
      const int gc = n0 + wc * 48 + j * 16 + lq;
      const float bv = b_o[gc];
#pragma unroll
      for (int r = 0; r < 4; ++r) {
        size_t off = (size_t)(gr + r) * HID_D + gc;
        out[off] = acc[ii][j][r] + bv + x[off];
      }
    }
  }
}

// ---------------- YaRN RoPE (q & k) -> bf16, reading bf16 qkv ----------------
__global__ __launch_bounds__(256) void ropev_kernel(const unsigned short* __restrict__ qkvb,
                                                    const int* __restrict__ positions,
                                                    unsigned short* __restrict__ qb,
                                                    unsigned short* __restrict__ kb) {
  int idx = blockIdx.x * 256 + threadIdx.x;
  int d = idx & 31;
  int head = (idx >> 5) % (NH + NKV);
  int t = idx / ((NH + NKV) * 32);
  float pw = (float)d * (1.0f / 32.0f);
  float extrap = expf(-pw * 11.9183905733f);
  float interp = extrap * (1.0f / 32.0f);
  float ramp = fminf(fmaxf(((float)d - 8.0f) * 0.1f, 0.0f), 1.0f);
  float invf = interp * ramp + extrap * (1.0f - ramp);
  float fr = (float)positions[t] * invf;
  float s, c;
  sincosf(fr, &s, &c);
  c *= MSCALE;
  s *= MSCALE;
  if (head < NH) {
    const unsigned short* b = qkvb + (size_t)t * QKV_N + head * HD + d;
    float x1 = bf2f(b[0]), x2 = bf2f(b[32]);
    unsigned short* ob = qb + (size_t)t * ATT_N + head * HD + d;
    ob[0] = f2bf(x1 * c - x2 * s);
    ob[32] = f2bf(x2 * c + x1 * s);
  } else {
    int gk = head - NH;
    const unsigned short* b = qkvb + (size_t)t * QKV_N + NH * HD + gk * HD + d;
    float x1 = bf2f(b[0]), x2 = bf2f(b[32]);
    unsigned short* ob = kb + (size_t)t * (NKV * HD) + gk * HD + d;
    ob[0] = f2bf(x1 * c - x2 * s);
    ob[32] = f2bf(x2 * c + x1 * s);
  }
}

// ---------------- V transpose via LDS (coalesced both sides): vt[g][d][t] ----------------
__global__ __launch_bounds__(256) void vtrans_kernel(const unsigned short* __restrict__ qkvb,
                                                     unsigned short* __restrict__ vt) {
  __shared__ unsigned short tile[64][72];   // pitch 144B (multiple of 16)
  const int g = blockIdx.x >> 5;
  const int t0 = (blockIdx.x & 31) << 6;
  const int r = threadIdx.x >> 3;           // 0..31
  const int c8 = (threadIdx.x & 7) << 3;    // 0,8,..,56
  const size_t vbase = (size_t)(NH + NKV) * HD + (size_t)g * HD;
#pragma unroll
  for (int hh = 0; hh < 2; ++hh) {
    int row = r + hh * 32;
    *(u16x8*)&tile[row][c8] =
        *(const u16x8*)(qkvb + (size_t)(t0 + row) * QKV_N + vbase + c8);
  }
  __syncthreads();
  const int d = threadIdx.x >> 2;           // 0..63
  const int ts = (threadIdx.x & 3) << 4;    // 0,16,32,48
  u16x8 v0, v1;
#pragma unroll
  for (int i = 0; i < 8; ++i) { v0[i] = tile[ts + i][d]; v1[i] = tile[ts + 8 + i][d]; }
  unsigned short* dst = vt + (size_t)(g * HD + d) * T_SEQ + t0 + ts;
  *(u16x8*)dst = v0;
  *(u16x8*)(dst + 8) = v1;
}

// ---------------- sliding-window attention with sinks (repacked O store) ----------------
__global__ __launch_bounds__(256) void attn_kernel(const unsigned short* __restrict__ qb,
                                                   const unsigned short* __restrict__ kb,
                                                   const unsigned short* __restrict__ vt,
                                                   const float* __restrict__ sinks,
                                                   unsigned short* __restrict__ att) {
  __shared__ unsigned short orep[4][16][72];   // per-wave O repack tile
  const int lane = threadIdx.x & 63;
  const int wid = threadIdx.x >> 6;
  const int q0 = blockIdx.x * 16;
  const int h = blockIdx.y * 4 + wid;
  const int g = h >> 3;
  const int lq = lane & 15;
  const int ro = lane >> 4;

  bf16x8 bq0, bq1;
  {
    const unsigned short* qp = qb + (size_t)(q0 + lq) * ATT_N + h * HD + ro * 8;
    bq0 = *(const bf16x8*)qp;
    bq1 = *(const bf16x8*)(qp + 32);
  }
  float m_run = sinks[h];
  float l_run = 1.0f;
  f32x4 o0 = {0.f, 0.f, 0.f, 0.f}, o1 = o0, o2 = o0, o3 = o0;
  const int qg = q0 + lq;
  const int jstart = (q0 >= WIN) ? q0 - WIN : 0;

  for (int jt = jstart; jt <= q0; jt += 32) {
    f32x4 st0 = {0.f, 0.f, 0.f, 0.f}, st1 = st0;
    {
      int kr = jt + ((lq >> 2) << 3) + (lq & 3);
      int kr0 = min(kr, T_SEQ - 1);
      int kr1 = min(kr + 4, T_SEQ - 1);
      const unsigned short* kp0 = kb + (size_t)kr0 * (NKV * HD) + g * HD + ro * 8;
      const unsigned short* kp1 = kb + (size_t)kr1 * (NKV * HD) + g * HD + ro * 8;
      bf16x8 ka0a = *(const bf16x8*)kp0;
      bf16x8 ka0b = *(const bf16x8*)(kp0 + 32);
      bf16x8 ka1a = *(const bf16x8*)kp1;
      bf16x8 ka1b = *(const bf16x8*)(kp1 + 32);
      st0 = __builtin_amdgcn_mfma_f32_16x16x32_bf16(ka0a, bq0, st0, 0, 0, 0);
      st0 = __builtin_amdgcn_mfma_f32_16x16x32_bf16(ka0b, bq1, st0, 0, 0, 0);
      st1 = __builtin_amdgcn_mfma_f32_16x16x32_bf16(ka1a, bq0, st1, 0, 0, 0);
      st1 = __builtin_amdgcn_mfma_f32_16x16x32_bf16(ka1b, bq1, st1, 0, 0, 0);
    }
    float p[8];
    float tmax = -3.0e30f;
#pragma unroll
    for (int r = 0; r < 4; ++r) {
      int jg0 = jt + ro * 8 + r;
      int jg1 = jg0 + 4;
      float s0 = (jg0 <= qg && (qg - jg0) < WIN) ? st0[r] * RSCALE : -3.0e30f;
      float s1 = (jg1 <= qg && (qg - jg1) < WIN) ? st1[r] * RSCALE : -3.0e30f;
      p[r] = s0;
      p[r + 4] = s1;
      tmax = fmaxf(tmax, fmaxf(s0, s1));
    }
    tmax = fmaxf(tmax, __shfl_xor(tmax, 16));
    tmax = fmaxf(tmax, __shfl_xor(tmax, 32));
    float m_new = fmaxf(m_run, tmax);
    float rescale = expf(m_run - m_new);
    float psum = 0.f;
    bf16x8 pa;
#pragma unroll
    for (int jj = 0; jj < 8; ++jj) {
      float pe = expf(p[jj] - m_new);
      psum += pe;
      pa[jj] = (short)f2bf(pe);
    }
    psum += __shfl_xor(psum, 16);
    psum += __shfl_xor(psum, 32);
    l_run = l_run * rescale + psum;
    m_run = m_new;
    f32x4 rs4;
#pragma unroll
    for (int r = 0; r < 4; ++r) rs4[r] = __shfl(rescale, ro * 4 + r);
    o0 *= rs4; o1 *= rs4; o2 *= rs4; o3 *= rs4;
    int tb = jt + ro * 8;
    if (tb > T_SEQ - 8) tb = T_SEQ - 8;
    const unsigned short* vp = vt + (size_t)(g * HD + lq) * T_SEQ + tb;
    bf16x8 v0 = *(const bf16x8*)vp;
    bf16x8 v1 = *(const bf16x8*)(vp + 16 * T_SEQ);
    bf16x8 v2 = *(const bf16x8*)(vp + 32 * T_SEQ);
    bf16x8 v3 = *(const bf16x8*)(vp + 48 * T_SEQ);
    o0 = __builtin_amdgcn_mfma_f32_16x16x32_bf16(pa, v0, o0, 0, 0, 0);
    o1 = __builtin_amdgcn_mfma_f32_16x16x32_bf16(pa, v1, o1, 0, 0, 0);
    o2 = __builtin_amdgcn_mfma_f32_16x16x32_bf16(pa, v2, o2, 0, 0, 0);
    o3 = __builtin_amdgcn_mfma_f32_16x16x32_bf16(pa, v3, o3, 0, 0, 0);
  }

  // per-wave LDS repack -> vectorized att stores (same-wave LDS ordering, no barrier)
#pragma unroll
  for (int r = 0; r < 4; ++r) {
    float lr = __shfl(l_run, ro * 4 + r);
    float inv = 1.0f / lr;
    int row = ro * 4 + r;
    orep[wid][row][lq]      = f2bf(o0[r] * inv);
    orep[wid][row][lq + 16] = f2bf(o1[r] * inv);
    orep[wid][row][lq + 32] = f2bf(o2[r] * inv);
    orep[wid][row][lq + 48] = f2bf(o3[r] * inv);
  }
  {
    const int row = lane >> 2;          // 0..15
    const int seg = (lane & 3) << 4;    // 0,16,32,48
    u16x8 w0 = *(const u16x8*)&orep[wid][row][seg];
    u16x8 w1 = *(const u16x8*)&orep[wid][row][seg + 8];
    unsigned short* op = att + (size_t)(q0 + row) * ATT_N + h * HD + seg;
    *(u16x8*)op = w0;
    *(u16x8*)(op + 8) = w1;
  }
}

extern "C" void kernel_launch(void* const* d_in, const int* in_sizes, int n_in,
                              void* d_out, int out_size, void* d_ws, size_t ws_size,
                              hipStream_t stream) {
  const float* x = (const float*)d_in[0];
  const int* pos = (const int*)d_in[1];
  const float* norm_w = (const float*)d_in[2];
  const float* w_qkv = (const float*)d_in[3];
  const float* b_qkv = (const float*)d_in[4];
  const float* w_o = (const float*)d_in[5];
  const float* b_o = (const float*)d_in[6];
  const float* sinks = (const float*)d_in[7];
  float* out = (float*)d_out;

  unsigned short* t_bf = (unsigned short*)d_ws;                        // [2048][2944]
  unsigned short* wq_bf = t_bf + (size_t)T_SEQ * KPAD;                 // [5120][2944]
  unsigned short* wo_bf = wq_bf + (size_t)QKV_N * KPAD;                // [2880][4096] (region sized NOPAD)
  unsigned short* qkv_bf = wo_bf + (size_t)NOPAD * ATT_N;              // [2048][5120] bf16
  unsigned short* qb = qkv_bf + (size_t)T_SEQ * QKV_N;                 // [2048][4096]
  unsigned short* kb = qb + (size_t)T_SEQ * ATT_N;                     // [2048][512]
  unsigned short* vt = kb + (size_t)T_SEQ * NKV * HD;                  // [8][64][2048]
  unsigned short* att = vt + (size_t)NKV * HD * T_SEQ;                 // [2048][4096]

  // 1. RMSNorm + w_qkv conversion
  pre_kernel<<<3072, 256, 0, stream>>>(x, norm_w, t_bf, w_qkv, wq_bf);
  // 2. QKV GEMM (160 blocks) + w_o conversion (96 blocks)
  qkv_fused_kernel<<<256, 512, 0, stream>>>(t_bf, wq_bf, qkv_bf, b_qkv, w_o, wo_bf);
  // 3. RoPE (q,k)
  ropev_kernel<<<ROPE_TOT / 256, 256, 0, stream>>>(qkv_bf, pos, qb, kb);
  // 4. V transpose (LDS, coalesced)
  vtrans_kernel<<<256, 256, 0, stream>>>(qkv_bf, vt);
  // 5. attention
  attn_kernel<<<dim3(T_SEQ / 16, NH / 4), 256, 0, stream>>>(qb, kb, vt, sinks, att);
  // 6. out projection: full-K 128x192 tiles, 240 blocks, direct store with bias + residual
  outproj192_kernel<<<240, 512, 0, stream>>>(att, wo_bf, out, b_o, x);
}